// Round 1
// baseline (42.890 us; speedup 1.0000x reference)
//
#include <hip/hip_runtime.h>

// Problem constants (fixed by the reference):
//   L=32768, N=32, E=1, H=1, BS=256 -> nb=128 blocks, 4096 (block,batch) problems.
// With E=H=1 the attention is rank-1: s_ij = a_i * k_j, softmax over j, dot with v.

#define LL  32768
#define NN  32
#define BSZ 256
#define NBLK (LL / BSZ)

__global__ __launch_bounds__(256, 2) void BlockCrossAttn_kernel(
    const float* __restrict__ q_in, const float* __restrict__ k_in,
    const float* __restrict__ v_in,
    const float* __restrict__ ipw,  const float* __restrict__ ipb,
    const float* __restrict__ opw,  const float* __restrict__ opb,
    float* __restrict__ out)
{
    const int blk = blockIdx.x >> 5;   // block index b in [0,128)
    const int n   = blockIdx.x & 31;   // batch index
    const int tid = threadIdx.x;       // row within block

    // Scalar params (wave-uniform loads -> scalar cache)
    const float wq = ipw[0], wk = ipw[1], wv = ipw[2];
    const float bq = ipb[0], bk = ipb[1], bv = ipb[2];
    const float wo = opw[0], bo = opb[0];

    __shared__ float sk[BSZ];
    __shared__ float sv[BSZ];
    __shared__ float sred[16];

    const int row  = blk * BSZ + tid;
    const int gidx = row * NN + n;

    const float qv = q_in[gidx];
    const float kv = k_in[gidx];
    const float vv = v_in[gidx];

    const float a     = fmaf(qv, wq, bq);   // scale = 1/sqrt(1) = 1
    const float kproj = fmaf(kv, wk, bk);
    const float vproj = fmaf(vv, wv, bv);
    sk[tid] = kproj;
    sv[tid] = vproj;

    // Block-wide kmax/kmin (row max of a_i*k_j is then a_i*kmax or a_i*kmin)
    float kmx = kproj, kmn = kproj;
    #pragma unroll
    for (int off = 32; off >= 1; off >>= 1) {
        kmx = fmaxf(kmx, __shfl_xor(kmx, off));
        kmn = fminf(kmn, __shfl_xor(kmn, off));
    }
    const int wid = tid >> 6;          // 4 waves per block
    if ((tid & 63) == 0) { sred[wid] = kmx; sred[wid + 8] = kmn; }
    __syncthreads();                   // also covers sk/sv visibility
    kmx = fmaxf(fmaxf(sred[0], sred[1]), fmaxf(sred[2], sred[3]));
    kmn = fminf(fminf(sred[8], sred[9]), fminf(sred[10], sred[11]));

    // Work in log2 domain: exp(x) = exp2(x * log2e); fold log2e into a.
    const float LOG2E = 1.4426950408889634f;
    const float al = a * LOG2E;
    const float m  = fmaxf(al * kmx, al * kmn);  // row max (log2 domain), >= all al*k_j

    float den0 = 0.f, den1 = 0.f, num0 = 0.f, num1 = 0.f;
    #pragma unroll 8
    for (int j = 0; j < BSZ; j += 2) {
        const float k0 = sk[j];
        const float k1 = sk[j + 1];
        const float p0 = __builtin_amdgcn_exp2f(fmaf(al, k0, -m));
        const float p1 = __builtin_amdgcn_exp2f(fmaf(al, k1, -m));
        den0 += p0;
        den1 += p1;
        num0 = fmaf(p0, sv[j],     num0);
        num1 = fmaf(p1, sv[j + 1], num1);
    }

    const float o = (num0 + num1) / (den0 + den1);
    out[gidx] = fmaf(o, wo, bo);
}

extern "C" void kernel_launch(void* const* d_in, const int* in_sizes, int n_in,
                              void* d_out, int out_size, void* d_ws, size_t ws_size,
                              hipStream_t stream) {
    const float* q   = (const float*)d_in[0];
    const float* k   = (const float*)d_in[1];
    const float* v   = (const float*)d_in[2];
    const float* ipw = (const float*)d_in[3];
    const float* ipb = (const float*)d_in[4];
    const float* opw = (const float*)d_in[5];
    const float* opb = (const float*)d_in[6];
    float* out = (float*)d_out;

    dim3 grid(NBLK * NN);   // 4096 workgroups: one per (block, batch)
    dim3 block(BSZ);        // one thread per row
    BlockCrossAttn_kernel<<<grid, block, 0, stream>>>(q, k, v, ipw, ipb, opw, opb, out);
}